// Round 10
// baseline (301.001 us; speedup 1.0000x reference)
//
#include <hip/hip_runtime.h>
#include <hip/hip_bf16.h>

#define EMB 128

typedef __attribute__((ext_vector_type(8))) short short8;   // 8 bf16 (4 VGPRs)
typedef __attribute__((ext_vector_type(4))) float floatx4;  // MFMA C/D

// 26 valid (ok, di, ol) message combos: deltas = {1,2,-1,-2}, ol = ok+delta in [0,8)
static constexpr int OKv[26] = {0,0,1,1,1,2,2,2,2,3,3,3,3,4,4,4,4,5,5,5,5,6,6,6,7,7};
static constexpr int DIv[26] = {0,1,0,1,2,0,1,2,3,0,1,2,3,0,1,2,3,0,1,2,3,0,2,3,2,3};
static constexpr int OLv[26] = {1,2,2,3,0,3,4,1,0,4,5,2,1,5,6,3,2,6,7,4,3,7,5,4,6,5};

__device__ __forceinline__ float2 ld2(const float* p) { return *(const float2*)p; }

// round-to-nearest-even bf16 bits of x, kept in the TOP 16 bits (low 16 zero)
__device__ __forceinline__ unsigned bf16_rne_hi(float x) {
  unsigned u = __float_as_uint(x);
  return (u + 0x7FFFu + ((u >> 16) & 1u)) & 0xFFFF0000u;
}
__device__ __forceinline__ float bf16hi_f(float x) {
  return __uint_as_float(bf16_rne_hi(x));
}
// HW packed cvt: a -> low 16, b -> high 16 (v_cvt_pk_bf16_f32 on gfx950)
__device__ __forceinline__ unsigned cvt_pk_bf16(float a, float b) {
  __hip_bfloat162 h = __float22bfloat162_rn(make_float2(a, b));
  unsigned r; __builtin_memcpy(&r, &h, 4); return r;
}

union FragU { unsigned u[4]; uint4 q; short8 v; };

// LOGICAL CHANNEL PERMUTATION (R9-verified): MFMA C physical position
// (u, n=lane&15) carries logical channel L(u,n) = 2*((u>>1)*16 + n) + (u&1).
// Wave wv computes u in {2wv, 2wv+1} -> lane (wv, m16) holds the ADJACENT
// logical pair c0 = 2*(wv*16+m16), c0+1. Only wfrag bakes the permutation.

// Fused prep, grid 73 x 512:
//  b 0..31  : lin32 row b — 4-way f-split + LDS reduce (R5-R9 version was
//             32x128 with a 128-deep load chain at 0.25 waves/CU: ~60-70 us
//             of exposed cold-HBM latency, the total-minus-main gap).
//  b 32..71 : w_conv -> B-fragment hi/lo pre-pack with permuted N.
//  b 72     : out[g] = b_pred[0].
__global__ __launch_bounds__(512) void prep_kernel(
    const float* __restrict__ emb_x,
    const float* __restrict__ w_ti,
    const float* __restrict__ b_ti,
    const float* __restrict__ w_conv,
    const float* __restrict__ b_pred,
    float* __restrict__ lin32,
    uint4* __restrict__ wfrag,
    float* __restrict__ out) {
  const int b = blockIdx.x, tid = threadIdx.x;
  if (b < 32) {
    __shared__ float red[4][EMB];
    const int e = tid & 127, fh = tid >> 7;      // fh in [0,4)
    const float* xr = emb_x + b * EMB;
    float s = 0.f;
    #pragma unroll 8
    for (int f = fh * 32; f < fh * 32 + 32; ++f)
      s = fmaf(xr[f], w_ti[f * EMB + e], s);
    red[fh][e] = s;
    __syncthreads();
    if (fh == 0)
      lin32[b * EMB + e] =
          b_ti[e] + ((red[0][e] + red[1][e]) + (red[2][e] + red[3][e]));
  } else if (b < 72) {
    const int id   = (b - 32) * 512 + tid;   // 320 frags * 64 lanes = 20480
    const int lane = id & 63;
    const int f    = id >> 6;
    const int pass = f & 1;           // 0 = hi, 1 = lo
    const int u    = (f >> 1) & 7;    // N-tile (physical)
    const int t    = (f >> 4) & 3;    // K-tile
    const int l    = f >> 6;          // layer
    const int q    = lane >> 4, n = lane & 15;
    const int cN   = 2 * ((u >> 1) * 16 + n) + (u & 1);   // logical out channel
    unsigned w[4] = {0u, 0u, 0u, 0u};
    #pragma unroll
    for (int j = 0; j < 8; ++j) {
      const int kk = t * 32 + q * 8 + j;    // logical in channel
      float val = w_conv[l * (EMB * EMB) + kk * EMB + cN];
      if (pass) val = val - bf16hi_f(val);
      const unsigned bb = bf16_rne_hi(val);
      w[j >> 1] |= (j & 1) ? bb : (bb >> 16);
    }
    wfrag[id] = make_uint4(w[0], w[1], w[2], w[3]);
  } else {
    if (tid < 64) out[tid] = b_pred[0];
  }
}

// Block = root node i. X stays in MFMA C-layout registers all 5 layers
// (M-row perm row(pair,k) = ((pair&1)+2*(k>>2))*16 + (pair>>1)*4 + (k&3)).
// Per layer: lane-local fp32 message pass (float2 ea from global/L1) ->
// single producer-side hi/lo bf16 pack written as uint32 DIRECTLY into the
// A-fragment LDS buffer (stride-68 rows: b32 writes 2-way free, b128 reads
// at the 8-sweep data floor) -> MFMA (2 N-tiles x 4 M-tiles x 4 kt x 3
// split-terms) -> residual+relu in registers. 2 barriers/layer, no epilogue
// round-trip, no redundant cvt. No occupancy attribute (R1/R6: forcing a
// budget makes the allocator spill ~0.5-1.6 GB).  [UNCHANGED from R9: 228 us]
__global__ __launch_bounds__(256)
void i2gnn_mfma(
    const int* __restrict__ x,
    const int* __restrict__ edge_attr,
    const int* __restrict__ tuplefeat,
    const float* __restrict__ emb_x,
    const float* __restrict__ emb_tf,
    const float* __restrict__ emb_ea,
    const float* __restrict__ lin32,
    const float* __restrict__ b_conv,
    const float* __restrict__ w_pred,
    const uint4* __restrict__ wfrag,
    float* __restrict__ out)
{
  __shared__ __align__(16) unsigned fragA[2 * 64 * 68];   // 34816 B, lo at +4352

  const int tid = threadIdx.x;
  const int wv = tid >> 6, lane = tid & 63;
  const int m16 = lane & 15, q2 = lane >> 4;
  const int pc = wv * 16 + m16;        // logical pair-column this lane produces
  const int c0 = pc * 2;               // logical channels c0, c0+1

  const int i = blockIdx.x;
  const int ibase = i & ~63, io = i & 63;
  const int g = i >> 6;

  // 26 edge attrs (4 bits each) — function of i only
  unsigned pk[4] = {0u, 0u, 0u, 0u};
  #pragma unroll
  for (int m = 0; m < 26; ++m) {
    const int kg = ibase + ((io + OKv[m]) & 63);
    const unsigned a = (unsigned)edge_attr[(kg << 2) + DIv[m]];
    pk[m >> 3] |= a << ((m & 7) * 4);
  }

  // tupleinit in C-layout: X[v][mt][r]; pair ps = mt&1 (this lane: 2*q2+ps),
  // k = (mt>>1)*4 + r; channels c0+v (adjacent logical pair).
  const int xi = x[i];
  const float2 xe = ld2(emb_x + xi * EMB + c0);
  float2 lj[2];
  #pragma unroll
  for (int ps = 0; ps < 2; ++ps) {
    const int jn = ibase + ((io + 2 * q2 + ps) & 63);
    lj[ps] = ld2(lin32 + x[jn] * EMB + c0);
  }
  floatx4 X[2][4];
  #pragma unroll
  for (int mt = 0; mt < 4; ++mt) {
    const int ps = mt & 1, kb = (mt >> 1) * 4;
    const int t0 = (i * 8 + 2 * q2 + ps) << 3;
    #pragma unroll
    for (int r = 0; r < 4; ++r) {
      const int2 tf2 = *(const int2*)(tuplefeat + 2 * (t0 + kb + r));
      const int row = (c0 < 64) ? tf2.x : tf2.y;   // c0,c0+1 in same half
      const float2 tf = ld2(emb_tf + row * 64 + (c0 & 63));
      X[0][mt][r] = xe.x * lj[ps].x * tf.x;
      X[1][mt][r] = xe.y * lj[ps].y * tf.y;
    }
  }

  for (int l = 0; l < 5; ++l) {
    // ---- message pass, lane-local on logical channels c0, c0+1 ----
    float acc[2][2][8];   // [v][ps][k]
    #pragma unroll
    for (int v = 0; v < 2; ++v)
      #pragma unroll
      for (int ps = 0; ps < 2; ++ps)
        #pragma unroll
        for (int k = 0; k < 8; ++k) acc[v][ps][k] = 0.f;
    #pragma unroll
    for (int m = 0; m < 26; ++m) {
      const unsigned attr = (pk[m >> 3] >> ((m & 7) * 4)) & 15u;
      const float2 e = ld2(emb_ea + attr * EMB + c0);
      const int ok = OKv[m], ol = OLv[m];
      const int mtb = 2 * (ol >> 2), rl = ol & 3;   // compile-time consts
      acc[0][0][ok] = fmaf(X[0][mtb + 0][rl], e.x, acc[0][0][ok]);
      acc[0][1][ok] = fmaf(X[0][mtb + 1][rl], e.x, acc[0][1][ok]);
      acc[1][0][ok] = fmaf(X[1][mtb + 0][rl], e.y, acc[1][0][ok]);
      acc[1][1][ok] = fmaf(X[1][mtb + 1][rl], e.y, acc[1][1][ok]);
    }
    // ---- single hi/lo pack, written straight into A-fragment layout ----
    #pragma unroll
    for (int ps = 0; ps < 2; ++ps)
      #pragma unroll
      for (int k = 0; k < 8; ++k) {
        const float a0 = acc[0][ps][k], a1 = acc[1][ps][k];
        const unsigned hi = cvt_pk_bf16(a0, a1);
        const float r0 = a0 - __uint_as_float(hi << 16);
        const float r1 = a1 - __uint_as_float(hi & 0xFFFF0000u);
        const int row = (ps + 2 * (k >> 2)) * 16 + q2 * 4 + (k & 3);
        fragA[row * 68 + pc] = hi;
        fragA[4352 + row * 68 + pc] = cvt_pk_bf16(r0, r1);
      }
    __syncthreads();

    // ---- MFMA: wave computes N-tiles {2wv, 2wv+1} for all 4 M-tiles ----
    floatx4 C[2][4];
    #pragma unroll
    for (int v = 0; v < 2; ++v)
      #pragma unroll
      for (int mt = 0; mt < 4; ++mt) C[v][mt] = (floatx4){0.f, 0.f, 0.f, 0.f};

    #pragma unroll
    for (int kt = 0; kt < 4; ++kt) {
      const uint4* wp0 = wfrag + ((((l * 4 + kt) * 8 + 2 * wv) * 2) << 6);
      FragU B0h, B0l, B1h, B1l;
      B0h.q = wp0[lane];        B0l.q = wp0[64 + lane];
      B1h.q = wp0[128 + lane];  B1l.q = wp0[192 + lane];
      #pragma unroll
      for (int mt = 0; mt < 4; ++mt) {
        const unsigned* fa = fragA + (mt * 16 + m16) * 68 + kt * 16 + q2 * 4;
        FragU Ah, Al;
        Ah.q = *(const uint4*)fa;
        Al.q = *(const uint4*)(fa + 4352);
        C[0][mt] = __builtin_amdgcn_mfma_f32_16x16x32_bf16(Ah.v, B0h.v, C[0][mt], 0, 0, 0);
        C[0][mt] = __builtin_amdgcn_mfma_f32_16x16x32_bf16(Al.v, B0h.v, C[0][mt], 0, 0, 0);
        C[0][mt] = __builtin_amdgcn_mfma_f32_16x16x32_bf16(Ah.v, B0l.v, C[0][mt], 0, 0, 0);
        C[1][mt] = __builtin_amdgcn_mfma_f32_16x16x32_bf16(Ah.v, B1h.v, C[1][mt], 0, 0, 0);
        C[1][mt] = __builtin_amdgcn_mfma_f32_16x16x32_bf16(Al.v, B1h.v, C[1][mt], 0, 0, 0);
        C[1][mt] = __builtin_amdgcn_mfma_f32_16x16x32_bf16(Ah.v, B1l.v, C[1][mt], 0, 0, 0);
      }
    }
    __syncthreads();   // reads done before next layer overwrites fragA

    // ---- residual + relu in registers (lane's C entries are c0, c0+1) ----
    const float2 bc = ld2(b_conv + l * EMB + c0);
    #pragma unroll
    for (int mt = 0; mt < 4; ++mt)
      #pragma unroll
      for (int r = 0; r < 4; ++r) {
        X[0][mt][r] += fmaxf(C[0][mt][r] + bc.x, 0.f);
        X[1][mt][r] += fmaxf(C[1][mt][r] + bc.y, 0.f);
      }
  }

  // ---- pooling: max over k per (v, pair), dot w_pred, xor-reduce, atomic ----
  const float2 wp = ld2(w_pred + c0);
  float s = 0.f;
  #pragma unroll
  for (int v = 0; v < 2; ++v) {
    float p0 = -3.4e38f, p1 = -3.4e38f;
    #pragma unroll
    for (int r = 0; r < 4; ++r) {
      p0 = fmaxf(p0, fmaxf(X[v][0][r], X[v][2][r]));   // ps=0: mt 0,2
      p1 = fmaxf(p1, fmaxf(X[v][1][r], X[v][3][r]));   // ps=1: mt 1,3
    }
    s = fmaf(p0 + p1, v ? wp.y : wp.x, s);
  }
  #pragma unroll
  for (int off = 32; off; off >>= 1) s += __shfl_xor(s, off, 64);
  if (lane == 0) atomicAdd(out + g, s);
}

extern "C" void kernel_launch(void* const* d_in, const int* in_sizes, int n_in,
                              void* d_out, int out_size, void* d_ws, size_t ws_size,
                              hipStream_t stream) {
  const int*   x         = (const int*)d_in[0];
  const int*   edge_attr = (const int*)d_in[1];
  const int*   tuplefeat = (const int*)d_in[2];
  const float* emb_x     = (const float*)d_in[12];
  const float* emb_ea    = (const float*)d_in[13];
  const float* emb_tf    = (const float*)d_in[14];
  const float* w_ti      = (const float*)d_in[15];
  const float* b_ti      = (const float*)d_in[16];
  const float* w_conv    = (const float*)d_in[17];
  const float* b_conv    = (const float*)d_in[18];
  const float* w_pred    = (const float*)d_in[19];
  const float* b_pred    = (const float*)d_in[20];
  float* out = (float*)d_out;
  float* lin32 = (float*)d_ws;                               // 32*128 fp32 = 16 KB
  uint4* wfrag = (uint4*)((char*)d_ws + 32 * EMB * 4);       // 320 KB B-fragments

  hipLaunchKernelGGL(prep_kernel, dim3(73), dim3(512), 0, stream,
                     emb_x, w_ti, b_ti, w_conv, b_pred, lin32, wfrag, out);
  hipLaunchKernelGGL(i2gnn_mfma, dim3(4096), dim3(256), 0, stream,
                     x, edge_attr, tuplefeat, emb_x, emb_tf, emb_ea, lin32,
                     b_conv, w_pred, wfrag, out);
}